// Round 9
// baseline (68.945 us; speedup 1.0000x reference)
//
#include <hip/hip_runtime.h>

#define BB 4
#define CIN 3
#define HH 512
#define WW 512
#define KK 9
#define COUT 3
#define HO 510
#define WO 510
#define HW (HH * WW)
#define HOWO (HO * WO)

// padded NHWC buffer: rows -3..514, cols -3..516 -> [518][520], origin (3,3)
#define PR 518
#define PC 520
#define PAD 3
#define XP_BYTES ((size_t)BB * PR * PC * 4 * sizeof(float))

typedef __fp16 h2 __attribute__((ext_vector_type(2)));

__device__ __forceinline__ h2 pkrtz(float a, float b) {
    return __builtin_amdgcn_cvt_pkrtz(a, b);
}
__device__ __forceinline__ float fdot2f(h2 a, h2 b, float c) {
    return __builtin_amdgcn_fdot2(a, b, c, false);
}
__device__ __forceinline__ h2 uint_as_h2(unsigned u) {
    return __builtin_bit_cast(h2, u);
}
__device__ __forceinline__ unsigned h2_as_uint(h2 h) {
    return __builtin_bit_cast(unsigned, h);
}
__device__ __forceinline__ float comp3(const float4& v, int c) {
    return c == 0 ? v.x : (c == 1 ? v.y : v.z);
}
// w1 element for channel ch at t2 = r*9 + s*3 + c (0 if t2 >= 27)
__device__ __forceinline__ float w1f(const float* w1, int ch, int t2) {
    if (t2 >= 27) return 0.f;
    const int r = t2 / 9, s = (t2 % 9) / 3, c = t2 % 3;
    return w1[ch * 27 + c * 9 + r * 3 + s];
}

// ---------------- kernel 1: NCHW -> padded NHW4 repack ----------------
__global__ __launch_bounds__(256) void repack_pad(
    const float* __restrict__ x, float4* __restrict__ xp)
{
    const int idx = blockIdx.x * blockDim.x + threadIdx.x;
    const int total = BB * PR * PC;
    if (idx >= total) return;
    const int b = idx / (PR * PC);
    const int rem = idx - b * (PR * PC);
    const int y = rem / PC;
    const int xc = rem - y * PC;
    const int ys = y - PAD;
    const int xs = xc - PAD;
    float4 v = make_float4(0.f, 0.f, 0.f, 0.f);
    if ((unsigned)ys < (unsigned)HH && (unsigned)xs < (unsigned)WW) {
        const float* xb = x + (size_t)b * CIN * HW;
        const int p = ys * WW + xs;
        v.x = xb[p];
        v.y = xb[HW + p];
        v.z = xb[2 * HW + p];
    }
    xp[idx] = v;
}

// ------ kernel 2: fused, phase-split: conv1 all taps -> addr -> gather -----
__global__ __launch_bounds__(256, 4) void deform_fused4(
    const float4* __restrict__ xp,  // [B][PR][PC] padded NHWC
    const float* __restrict__ w1,   // [18][3][3][3]
    const float* __restrict__ b1,   // [18]
    const float* __restrict__ w2,   // [3][3][3][3]
    const float* __restrict__ b2,   // [3]
    float* __restrict__ out)        // [B][3][HO][WO]
{
    __shared__ uint4 s_w1h[KK * 7];
    __shared__ float s_b[18];
    __shared__ float s_w2[KK * 12];  // [k][12], first 9 = o*3+c
    __shared__ float s_b2[COUT];

    if (threadIdx.x < KK * 7) {
        const int k = threadIdx.x / 7;
        const int gg = threadIdx.x % 7;
        float wy[4], wx[4];
#pragma unroll
        for (int q = 0; q < 4; ++q) {
            const int t2 = 4 * gg + q;
            wy[q] = w1f(w1, 2 * k, t2);
            wx[q] = w1f(w1, 2 * k + 1, t2);
        }
        uint4 u;
        u.x = h2_as_uint(pkrtz(wy[0], wy[1]));
        u.y = h2_as_uint(pkrtz(wx[0], wx[1]));
        u.z = h2_as_uint(pkrtz(wy[2], wy[3]));
        u.w = h2_as_uint(pkrtz(wx[2], wx[3]));
        s_w1h[threadIdx.x] = u;
    }
    for (int t = threadIdx.x; t < KK * 12; t += 256) {
        const int k = t / 12;
        const int q = t % 12;
        s_w2[t] = (q < 9) ? w2[(q / 3) * 27 + (q % 3) * 9 + k] : 0.f;
    }
    if (threadIdx.x < 18) s_b[threadIdx.x] = b1[threadIdx.x];
    if (threadIdx.x < COUT) s_b2[threadIdx.x] = b2[threadIdx.x];
    __syncthreads();

    constexpr int WP = WO / 2;  // 255
    const int idx = blockIdx.x * 256 + threadIdx.x;
    if (idx >= BB * HO * WP) return;
    const int jp = idx % WP;
    const int t1 = idx / WP;
    const int i = t1 % HO;
    const int b = t1 / HO;
    const int j = jp * 2;

    const float4* xb4 = xp + (size_t)b * (PR * PC);

    // ---- phase 1: patch, f16 packing, conv1 for ALL taps -> f32 offsets ----
    float4 pat[3][4];
#pragma unroll
    for (int r = 0; r < 3; ++r)
#pragma unroll
        for (int col = 0; col < 4; ++col)
            pat[r][col] = xb4[(i + r + PAD) * PC + (j + col + PAD)];

    h2 ph0[14], ph1[14];
#pragma unroll
    for (int g = 0; g < 14; ++g) {
        const int ta = 2 * g;
        const int ra = ta / 9, sa = (ta % 9) / 3, ca = ta % 3;
        const float a0 = comp3(pat[ra][sa], ca);
        const float a1 = comp3(pat[ra][sa + 1], ca);
        float b0 = 0.f, b1v = 0.f;
        if (2 * g + 1 < 27) {
            const int tb = 2 * g + 1;
            const int rb = tb / 9, sb = (tb % 9) / 3, cb = tb % 3;
            b0 = comp3(pat[rb][sb], cb);
            b1v = comp3(pat[rb][sb + 1], cb);
        }
        ph0[g] = pkrtz(a0, b0);
        ph1[g] = pkrtz(a1, b1v);
    }

    float dy0[KK], dx0[KK], dy1[KK], dx1[KK];
#pragma unroll
    for (int k = 0; k < KK; ++k) {
        float ay0 = 0.f, ax0 = 0.f, ay1 = 0.f, ax1 = 0.f;
        float by0 = 0.f, bx0 = 0.f, by1 = 0.f, bx1 = 0.f;
        const uint4* wk = &s_w1h[k * 7];
#pragma unroll
        for (int gg = 0; gg < 7; ++gg) {
            const uint4 w = wk[gg];
            const h2 wyA = uint_as_h2(w.x);
            const h2 wxA = uint_as_h2(w.y);
            const h2 wyB = uint_as_h2(w.z);
            const h2 wxB = uint_as_h2(w.w);
            ay0 = fdot2f(wyA, ph0[2 * gg], ay0);
            ax0 = fdot2f(wxA, ph0[2 * gg], ax0);
            ay1 = fdot2f(wyA, ph1[2 * gg], ay1);
            ax1 = fdot2f(wxA, ph1[2 * gg], ax1);
            by0 = fdot2f(wyB, ph0[2 * gg + 1], by0);
            bx0 = fdot2f(wxB, ph0[2 * gg + 1], bx0);
            by1 = fdot2f(wyB, ph1[2 * gg + 1], by1);
            bx1 = fdot2f(wxB, ph1[2 * gg + 1], bx1);
        }
        dy0[k] = s_b[2 * k] + (ay0 + by0);
        dx0[k] = s_b[2 * k + 1] + (ax0 + bx0);
        dy1[k] = s_b[2 * k] + (ay1 + by1);
        dx1[k] = s_b[2 * k + 1] + (ax1 + bx1);
    }

    // ---- phase 2a: all corner addresses + fractions (loads can hoist) ----
    const float fi3 = (float)i + (float)PAD;
    const float fj3 = (float)j + (float)PAD;
    int A0[KK], A1[KK];
    float fy0[KK], fx0[KK], fy1[KK], fx1[KK];
#pragma unroll
    for (int k = 0; k < KK; ++k) {
        const float ry = fi3 + (float)(k / 3);
        const float syp0 = ry + dy0[k];
        const float sxp0 = fj3 + (float)(k % 3) + dx0[k];
        const int y0 = (int)syp0;  // trunc == floor (always > 0)
        const int x0 = (int)sxp0;
        fy0[k] = syp0 - (float)y0;
        fx0[k] = sxp0 - (float)x0;
        A0[k] = y0 * PC + x0;
        const float syp1 = ry + dy1[k];
        const float sxp1 = fj3 + (float)(k % 3 + 1) + dx1[k];
        const int y1 = (int)syp1;
        const int x1 = (int)sxp1;
        fy1[k] = syp1 - (float)y1;
        fx1[k] = sxp1 - (float)x1;
        A1[k] = y1 * PC + x1;
    }

    // ---- phase 2b: gather + bilinear + conv2, fully unrolled ----
    float acc00 = s_b2[0], acc01 = s_b2[1], acc02 = s_b2[2];
    float acc10 = s_b2[0], acc11 = s_b2[1], acc12 = s_b2[2];
#pragma unroll
    for (int k = 0; k < KK; ++k) {
        const float4* wk4 = reinterpret_cast<const float4*>(&s_w2[k * 12]);
        const float4 a = wk4[0];
        const float4 bbv = wk4[1];
        const float cw = s_w2[k * 12 + 8];

        {
            const int a00 = A0[k];
            const float4 c00 = xb4[a00];
            const float4 c01 = xb4[a00 + 1];
            const float4 c10 = xb4[a00 + PC];
            const float4 c11 = xb4[a00 + PC + 1];
            const float fy = fy0[k], fx = fx0[k];
            const float wy0 = 1.f - fy, wx0 = 1.f - fx;
            const float w00 = wy0 * wx0, w01 = wy0 * fx;
            const float w10 = fy * wx0, w11 = fy * fx;
            const float v0 = w00 * c00.x + w01 * c01.x + w10 * c10.x + w11 * c11.x;
            const float v1 = w00 * c00.y + w01 * c01.y + w10 * c10.y + w11 * c11.y;
            const float v2 = w00 * c00.z + w01 * c01.z + w10 * c10.z + w11 * c11.z;
            acc00 += a.x * v0 + a.y * v1 + a.z * v2;
            acc01 += a.w * v0 + bbv.x * v1 + bbv.y * v2;
            acc02 += bbv.z * v0 + bbv.w * v1 + cw * v2;
        }
        {
            const int a00 = A1[k];
            const float4 c00 = xb4[a00];
            const float4 c01 = xb4[a00 + 1];
            const float4 c10 = xb4[a00 + PC];
            const float4 c11 = xb4[a00 + PC + 1];
            const float fy = fy1[k], fx = fx1[k];
            const float wy0 = 1.f - fy, wx0 = 1.f - fx;
            const float w00 = wy0 * wx0, w01 = wy0 * fx;
            const float w10 = fy * wx0, w11 = fy * fx;
            const float v0 = w00 * c00.x + w01 * c01.x + w10 * c10.x + w11 * c11.x;
            const float v1 = w00 * c00.y + w01 * c01.y + w10 * c10.y + w11 * c11.y;
            const float v2 = w00 * c00.z + w01 * c01.z + w10 * c10.z + w11 * c11.z;
            acc10 += a.x * v0 + a.y * v1 + a.z * v2;
            acc11 += a.w * v0 + bbv.x * v1 + bbv.y * v2;
            acc12 += bbv.z * v0 + bbv.w * v1 + cw * v2;
        }
    }

    float* ob = out + (size_t)b * COUT * HOWO + (size_t)i * WO + j;
    {
        float2 st;
        st.x = acc00; st.y = acc10;
        *reinterpret_cast<float2*>(&ob[0 * HOWO]) = st;
        st.x = acc01; st.y = acc11;
        *reinterpret_cast<float2*>(&ob[1 * HOWO]) = st;
        st.x = acc02; st.y = acc12;
        *reinterpret_cast<float2*>(&ob[2 * HOWO]) = st;
    }
}

// ---------------- fallback: R0-style fully fused (no workspace) ----------
__global__ __launch_bounds__(256) void deform_fused_kernel(
    const float* __restrict__ x, const float* __restrict__ w1,
    const float* __restrict__ b1, const float* __restrict__ w2,
    const float* __restrict__ b2, float* __restrict__ out)
{
    __shared__ float s_w1[18 * 27];
    __shared__ float s_b1[18];
    __shared__ float s_w2[COUT * CIN * KK];
    __shared__ float s_b2[COUT];
    for (int t = threadIdx.x; t < 18 * 27; t += blockDim.x) s_w1[t] = w1[t];
    if (threadIdx.x < 18) s_b1[threadIdx.x] = b1[threadIdx.x];
    if (threadIdx.x < COUT * CIN * KK) s_w2[threadIdx.x] = w2[threadIdx.x];
    if (threadIdx.x < COUT) s_b2[threadIdx.x] = b2[threadIdx.x];
    __syncthreads();
    const int idx = blockIdx.x * blockDim.x + threadIdx.x;
    if (idx >= BB * HOWO) return;
    const int j = idx % WO;
    const int tmp = idx / WO;
    const int i = tmp % HO;
    const int b = tmp / HO;
    const float* xb = x + (size_t)b * CIN * HW;
    float patch[CIN][3][3];
#pragma unroll
    for (int c = 0; c < CIN; ++c)
#pragma unroll
        for (int r = 0; r < 3; ++r)
#pragma unroll
            for (int s = 0; s < 3; ++s)
                patch[c][r][s] = xb[c * HW + (i + r) * WW + (j + s)];
    float acc0 = s_b2[0], acc1 = s_b2[1], acc2 = s_b2[2];
#pragma unroll
    for (int k = 0; k < KK; ++k) {
        const int ky = k / 3, kx = k % 3;
        float dy = s_b1[2 * k], dx = s_b1[2 * k + 1];
        const float* wy = &s_w1[(2 * k) * 27];
        const float* wx = &s_w1[(2 * k + 1) * 27];
        int t = 0;
#pragma unroll
        for (int c = 0; c < CIN; ++c)
#pragma unroll
            for (int r = 0; r < 3; ++r)
#pragma unroll
                for (int s = 0; s < 3; ++s, ++t) {
                    const float pv = patch[c][r][s];
                    dy += pv * wy[t];
                    dx += pv * wx[t];
                }
        const float sy = (float)(i + ky) + dy;
        const float sx = (float)(j + kx) + dx;
        const float y0f = floorf(sy), x0f = floorf(sx);
        const float fy = sy - y0f, fx = sx - x0f;
        const int y0 = (int)y0f, x0 = (int)x0f;
        float v0 = 0.f, v1 = 0.f, v2 = 0.f;
#pragma unroll
        for (int cy = 0; cy < 2; ++cy) {
            const int iy = y0 + cy;
            const float wyf = cy ? fy : (1.f - fy);
            const bool vy = (iy >= 0) && (iy < HH);
            const int iyc = iy < 0 ? 0 : (iy > HH - 1 ? HH - 1 : iy);
#pragma unroll
            for (int cx = 0; cx < 2; ++cx) {
                const int ix = x0 + cx;
                const float wxf = cx ? fx : (1.f - fx);
                const bool vx = (ix >= 0) && (ix < WW);
                const int ixc = ix < 0 ? 0 : (ix > WW - 1 ? WW - 1 : ix);
                const float wgt = (vy && vx) ? (wyf * wxf) : 0.f;
                const int off = iyc * WW + ixc;
                v0 += wgt * xb[0 * HW + off];
                v1 += wgt * xb[1 * HW + off];
                v2 += wgt * xb[2 * HW + off];
            }
        }
#pragma unroll
        for (int o = 0; o < COUT; ++o) {
            const float c0 = s_w2[(o * CIN + 0) * KK + k];
            const float c1 = s_w2[(o * CIN + 1) * KK + k];
            const float c2 = s_w2[(o * CIN + 2) * KK + k];
            const float contrib = c0 * v0 + c1 * v1 + c2 * v2;
            if (o == 0) acc0 += contrib;
            else if (o == 1) acc1 += contrib;
            else acc2 += contrib;
        }
    }
    float* ob = out + (size_t)b * COUT * HOWO + (size_t)i * WO + j;
    ob[0 * HOWO] = acc0;
    ob[1 * HOWO] = acc1;
    ob[2 * HOWO] = acc2;
}

extern "C" void kernel_launch(void* const* d_in, const int* in_sizes, int n_in,
                              void* d_out, int out_size, void* d_ws, size_t ws_size,
                              hipStream_t stream) {
    const float* x  = (const float*)d_in[0];
    const float* w1 = (const float*)d_in[1];
    const float* b1 = (const float*)d_in[2];
    const float* w2 = (const float*)d_in[3];
    const float* b2 = (const float*)d_in[4];
    float* out = (float*)d_out;

    if (ws_size >= XP_BYTES) {
        float4* xp = (float4*)d_ws;
        {
            const int total = BB * PR * PC;
            repack_pad<<<(total + 255) / 256, 256, 0, stream>>>(x, xp);
        }
        {
            const int total = BB * HO * (WO / 2);
            deform_fused4<<<(total + 255) / 256, 256, 0, stream>>>(
                xp, w1, b1, w2, b2, out);
        }
    } else {
        const int total = BB * HOWO;
        deform_fused_kernel<<<(total + 255) / 256, 256, 0, stream>>>(
            x, w1, b1, w2, b2, out);
    }
}

// Round 10
// 44.082 us; speedup vs baseline: 1.5640x; 1.5640x over previous
//
#include <hip/hip_runtime.h>

#define BB 4
#define CIN 3
#define HH 512
#define WW 512
#define KK 9
#define COUT 3
#define HO 510
#define WO 510
#define HW (HH * WW)
#define HOWO (HO * WO)

// padded f16 NHWC buffer: [B][PR][PC] x uint2 (c0c1, c2pad), origin (PADR, PADC)
#define PR 518
#define PC 520
#define PADR 3
#define PADC 4
#define XP_BYTES ((size_t)BB * PR * PC * sizeof(uint2))

typedef __fp16 h2 __attribute__((ext_vector_type(2)));

__device__ __forceinline__ h2 pkrtz(float a, float b) {
    return __builtin_amdgcn_cvt_pkrtz(a, b);
}
__device__ __forceinline__ float fdot2f(h2 a, h2 b, float c) {
    return __builtin_amdgcn_fdot2(a, b, c, false);
}
__device__ __forceinline__ h2 uint_as_h2(unsigned u) {
    return __builtin_bit_cast(h2, u);
}
__device__ __forceinline__ unsigned h2_as_uint(h2 h) {
    return __builtin_bit_cast(unsigned, h);
}
// w1 element: channel ch, input channel c, kernel row r, col s
__device__ __forceinline__ float w1e(const float* w1, int ch, int c, int r, int s) {
    return w1[ch * 27 + c * 9 + r * 3 + s];
}

// ---------------- kernel 1: NCHW f32 -> padded f16 NHWC ----------------
__global__ __launch_bounds__(256) void repack_padh(
    const float* __restrict__ x, uint2* __restrict__ xp)
{
    const int idx = blockIdx.x * blockDim.x + threadIdx.x;
    const int total = BB * PR * PC;
    if (idx >= total) return;
    const int b = idx / (PR * PC);
    const int rem = idx - b * (PR * PC);
    const int y = rem / PC;
    const int xc = rem - y * PC;
    const int ys = y - PADR;
    const int xs = xc - PADC;
    uint2 v = make_uint2(0u, 0u);
    if ((unsigned)ys < (unsigned)HH && (unsigned)xs < (unsigned)WW) {
        const float* xb = x + (size_t)b * CIN * HW;
        const int p = ys * WW + xs;
        v.x = h2_as_uint(pkrtz(xb[p], xb[HW + p]));
        v.y = h2_as_uint(pkrtz(xb[2 * HW + p], 0.f));
    }
    xp[idx] = v;
}

// ------ kernel 2: fused; phase A conv1 -> 18 packed dwords; phase B gather --
__global__ __launch_bounds__(256) void deform_fused5(
    const uint2* __restrict__ xp,   // [B][PR][PC] padded f16 NHWC
    const float* __restrict__ w1,   // [18][3][3][3]
    const float* __restrict__ b1,   // [18]
    const float* __restrict__ w2,   // [3][3][3][3]
    const float* __restrict__ b2,   // [3]
    float* __restrict__ out)        // [B][3][HO][WO]
{
    // s_w1h[k*9+pos] = {wy_c01, wy_c2x, wx_c01, wx_c2x} as h2 dwords,
    // pos = r*3+s; channel pair for tap k = (2k, 2k+1).
    __shared__ uint4 s_w1h[KK * 9];
    __shared__ float s_b[18];
    __shared__ float s_w2[KK * 12];  // [k][12], first 9 = o*3+c
    __shared__ float s_b2[COUT];

    if (threadIdx.x < KK * 9) {
        const int k = threadIdx.x / 9;
        const int pos = threadIdx.x % 9;
        const int r = pos / 3, s = pos % 3;
        uint4 u;
        u.x = h2_as_uint(pkrtz(w1e(w1, 2 * k, 0, r, s), w1e(w1, 2 * k, 1, r, s)));
        u.y = h2_as_uint(pkrtz(w1e(w1, 2 * k, 2, r, s), 0.f));
        u.z = h2_as_uint(pkrtz(w1e(w1, 2 * k + 1, 0, r, s), w1e(w1, 2 * k + 1, 1, r, s)));
        u.w = h2_as_uint(pkrtz(w1e(w1, 2 * k + 1, 2, r, s), 0.f));
        s_w1h[threadIdx.x] = u;
    }
    for (int t = threadIdx.x; t < KK * 12; t += 256) {
        const int k = t / 12;
        const int q = t % 12;
        s_w2[t] = (q < 9) ? w2[(q / 3) * 27 + (q % 3) * 9 + k] : 0.f;
    }
    if (threadIdx.x < 18) s_b[threadIdx.x] = b1[threadIdx.x];
    if (threadIdx.x < COUT) s_b2[threadIdx.x] = b2[threadIdx.x];
    __syncthreads();

    constexpr int WP = WO / 2;  // 255
    const int idx = blockIdx.x * 256 + threadIdx.x;
    if (idx >= BB * HO * WP) return;
    const int jp = idx % WP;
    const int t1 = idx / WP;
    const int i = t1 % HO;
    const int b = t1 / HO;
    const int j = jp * 2;

    const uint2* xb2 = xp + (size_t)b * (PR * PC);

    // ---- phase A: patch (f16 native) + conv1 -> packed offsets pk0/pk1 ----
    h2 p01[3][4], p2p[3][4];
#pragma unroll
    for (int r = 0; r < 3; ++r) {
        const int base = (i + r + PADR) * PC + (j + PADC);  // even elem idx
        const uint4 qa = *reinterpret_cast<const uint4*>(xb2 + base);
        const uint4 qb = *reinterpret_cast<const uint4*>(xb2 + base + 2);
        p01[r][0] = uint_as_h2(qa.x); p2p[r][0] = uint_as_h2(qa.y);
        p01[r][1] = uint_as_h2(qa.z); p2p[r][1] = uint_as_h2(qa.w);
        p01[r][2] = uint_as_h2(qb.x); p2p[r][2] = uint_as_h2(qb.y);
        p01[r][3] = uint_as_h2(qb.z); p2p[r][3] = uint_as_h2(qb.w);
    }

    unsigned pk0[KK], pk1[KK];  // packed (dy,dx) per tap per pixel
#pragma unroll
    for (int k = 0; k < KK; ++k) {
        float dy0 = s_b[2 * k], dx0 = s_b[2 * k + 1];
        float dy1 = dy0, dx1 = dx0;
        const uint4* wk = &s_w1h[k * 9];
#pragma unroll
        for (int r = 0; r < 3; ++r)
#pragma unroll
            for (int s = 0; s < 3; ++s) {
                const uint4 wq = wk[r * 3 + s];
                const h2 wy01 = uint_as_h2(wq.x);
                const h2 wy2x = uint_as_h2(wq.y);
                const h2 wx01 = uint_as_h2(wq.z);
                const h2 wx2x = uint_as_h2(wq.w);
                dy0 = fdot2f(wy01, p01[r][s], dy0);
                dy0 = fdot2f(wy2x, p2p[r][s], dy0);
                dx0 = fdot2f(wx01, p01[r][s], dx0);
                dx0 = fdot2f(wx2x, p2p[r][s], dx0);
                dy1 = fdot2f(wy01, p01[r][s + 1], dy1);
                dy1 = fdot2f(wy2x, p2p[r][s + 1], dy1);
                dx1 = fdot2f(wx01, p01[r][s + 1], dx1);
                dx1 = fdot2f(wx2x, p2p[r][s + 1], dx1);
            }
        pk0[k] = h2_as_uint(pkrtz(dy0, dx0));
        pk1[k] = h2_as_uint(pkrtz(dy1, dx1));
    }

    // ---- phase B: gather + bilinear (f32) + conv2, fully unrolled ----
    const float fi = (float)(i + PADR);
    const float fj = (float)(j + PADC);
    float acc00 = s_b2[0], acc01 = s_b2[1], acc02 = s_b2[2];
    float acc10 = s_b2[0], acc11 = s_b2[1], acc12 = s_b2[2];

#pragma unroll
    for (int k = 0; k < KK; ++k) {
        const float4* wk4 = reinterpret_cast<const float4*>(&s_w2[k * 12]);
        const float4 a = wk4[0];
        const float4 bbv = wk4[1];
        const float cw = s_w2[k * 12 + 8];
        const float ry = fi + (float)(k / 3);
        const float rx = fj + (float)(k % 3);

#pragma unroll
        for (int p = 0; p < 2; ++p) {
            const h2 d = uint_as_h2(p ? pk1[k] : pk0[k]);
            const float syp = ry + (float)d.x;             // always > 0
            const float sxp = rx + (float)p + (float)d.y;  // always > 0
            const int y0 = (int)syp;  // trunc == floor
            const int x0 = (int)sxp;
            const float fy = syp - (float)y0;
            const float fx = sxp - (float)x0;

            const int a00 = y0 * PC + x0;
            const uint2 c00 = xb2[a00];
            const uint2 c01 = xb2[a00 + 1];
            const uint2 c10 = xb2[a00 + PC];
            const uint2 c11 = xb2[a00 + PC + 1];

            const float wy0 = 1.f - fy, wx0 = 1.f - fx;
            const float w00 = wy0 * wx0, w01 = wy0 * fx;
            const float w10 = fy * wx0, w11 = fy * fx;

            const h2 g00 = uint_as_h2(c00.x), e00 = uint_as_h2(c00.y);
            const h2 g01 = uint_as_h2(c01.x), e01 = uint_as_h2(c01.y);
            const h2 g10 = uint_as_h2(c10.x), e10 = uint_as_h2(c10.y);
            const h2 g11 = uint_as_h2(c11.x), e11 = uint_as_h2(c11.y);

            const float v0 = w00 * (float)g00.x + w01 * (float)g01.x +
                             w10 * (float)g10.x + w11 * (float)g11.x;
            const float v1 = w00 * (float)g00.y + w01 * (float)g01.y +
                             w10 * (float)g10.y + w11 * (float)g11.y;
            const float v2 = w00 * (float)e00.x + w01 * (float)e01.x +
                             w10 * (float)e10.x + w11 * (float)e11.x;

            const float r0 = a.x * v0 + a.y * v1 + a.z * v2;
            const float r1 = a.w * v0 + bbv.x * v1 + bbv.y * v2;
            const float r2 = bbv.z * v0 + bbv.w * v1 + cw * v2;
            if (p == 0) {
                acc00 += r0; acc01 += r1; acc02 += r2;
            } else {
                acc10 += r0; acc11 += r1; acc12 += r2;
            }
        }
    }

    float* ob = out + (size_t)b * COUT * HOWO + (size_t)i * WO + j;
    {
        float2 st;
        st.x = acc00; st.y = acc10;
        *reinterpret_cast<float2*>(&ob[0 * HOWO]) = st;
        st.x = acc01; st.y = acc11;
        *reinterpret_cast<float2*>(&ob[1 * HOWO]) = st;
        st.x = acc02; st.y = acc12;
        *reinterpret_cast<float2*>(&ob[2 * HOWO]) = st;
    }
}

// ---------------- fallback: R0-style fully fused (no workspace) ----------
__global__ __launch_bounds__(256) void deform_fused_kernel(
    const float* __restrict__ x, const float* __restrict__ w1,
    const float* __restrict__ b1, const float* __restrict__ w2,
    const float* __restrict__ b2, float* __restrict__ out)
{
    __shared__ float s_w1[18 * 27];
    __shared__ float s_b1[18];
    __shared__ float s_w2[COUT * CIN * KK];
    __shared__ float s_b2[COUT];
    for (int t = threadIdx.x; t < 18 * 27; t += blockDim.x) s_w1[t] = w1[t];
    if (threadIdx.x < 18) s_b1[threadIdx.x] = b1[threadIdx.x];
    if (threadIdx.x < COUT * CIN * KK) s_w2[threadIdx.x] = w2[threadIdx.x];
    if (threadIdx.x < COUT) s_b2[threadIdx.x] = b2[threadIdx.x];
    __syncthreads();
    const int idx = blockIdx.x * blockDim.x + threadIdx.x;
    if (idx >= BB * HOWO) return;
    const int j = idx % WO;
    const int tmp = idx / WO;
    const int i = tmp % HO;
    const int b = tmp / HO;
    const float* xb = x + (size_t)b * CIN * HW;
    float patch[CIN][3][3];
#pragma unroll
    for (int c = 0; c < CIN; ++c)
#pragma unroll
        for (int r = 0; r < 3; ++r)
#pragma unroll
            for (int s = 0; s < 3; ++s)
                patch[c][r][s] = xb[c * HW + (i + r) * WW + (j + s)];
    float acc0 = s_b2[0], acc1 = s_b2[1], acc2 = s_b2[2];
#pragma unroll
    for (int k = 0; k < KK; ++k) {
        const int ky = k / 3, kx = k % 3;
        float dy = s_b1[2 * k], dx = s_b1[2 * k + 1];
        const float* wy = &s_w1[(2 * k) * 27];
        const float* wx = &s_w1[(2 * k + 1) * 27];
        int t = 0;
#pragma unroll
        for (int c = 0; c < CIN; ++c)
#pragma unroll
            for (int r = 0; r < 3; ++r)
#pragma unroll
                for (int s = 0; s < 3; ++s, ++t) {
                    const float pv = patch[c][r][s];
                    dy += pv * wy[t];
                    dx += pv * wx[t];
                }
        const float sy = (float)(i + ky) + dy;
        const float sx = (float)(j + kx) + dx;
        const float y0f = floorf(sy), x0f = floorf(sx);
        const float fy = sy - y0f, fx = sx - x0f;
        const int y0 = (int)y0f, x0 = (int)x0f;
        float v0 = 0.f, v1 = 0.f, v2 = 0.f;
#pragma unroll
        for (int cy = 0; cy < 2; ++cy) {
            const int iy = y0 + cy;
            const float wyf = cy ? fy : (1.f - fy);
            const bool vy = (iy >= 0) && (iy < HH);
            const int iyc = iy < 0 ? 0 : (iy > HH - 1 ? HH - 1 : iy);
#pragma unroll
            for (int cx = 0; cx < 2; ++cx) {
                const int ix = x0 + cx;
                const float wxf = cx ? fx : (1.f - fx);
                const bool vx = (ix >= 0) && (ix < WW);
                const int ixc = ix < 0 ? 0 : (ix > WW - 1 ? WW - 1 : ix);
                const float wgt = (vy && vx) ? (wyf * wxf) : 0.f;
                const int off = iyc * WW + ixc;
                v0 += wgt * xb[0 * HW + off];
                v1 += wgt * xb[1 * HW + off];
                v2 += wgt * xb[2 * HW + off];
            }
        }
#pragma unroll
        for (int o = 0; o < COUT; ++o) {
            const float c0 = s_w2[(o * CIN + 0) * KK + k];
            const float c1 = s_w2[(o * CIN + 1) * KK + k];
            const float c2 = s_w2[(o * CIN + 2) * KK + k];
            const float contrib = c0 * v0 + c1 * v1 + c2 * v2;
            if (o == 0) acc0 += contrib;
            else if (o == 1) acc1 += contrib;
            else acc2 += contrib;
        }
    }
    float* ob = out + (size_t)b * COUT * HOWO + (size_t)i * WO + j;
    ob[0 * HOWO] = acc0;
    ob[1 * HOWO] = acc1;
    ob[2 * HOWO] = acc2;
}

extern "C" void kernel_launch(void* const* d_in, const int* in_sizes, int n_in,
                              void* d_out, int out_size, void* d_ws, size_t ws_size,
                              hipStream_t stream) {
    const float* x  = (const float*)d_in[0];
    const float* w1 = (const float*)d_in[1];
    const float* b1 = (const float*)d_in[2];
    const float* w2 = (const float*)d_in[3];
    const float* b2 = (const float*)d_in[4];
    float* out = (float*)d_out;

    if (ws_size >= XP_BYTES) {
        uint2* xp = (uint2*)d_ws;
        {
            const int total = BB * PR * PC;
            repack_padh<<<(total + 255) / 256, 256, 0, stream>>>(x, xp);
        }
        {
            const int total = BB * HO * (WO / 2);
            deform_fused5<<<(total + 255) / 256, 256, 0, stream>>>(
                xp, w1, b1, w2, b2, out);
        }
    } else {
        const int total = BB * HOWO;
        deform_fused_kernel<<<(total + 255) / 256, 256, 0, stream>>>(
            x, w1, b1, w2, b2, out);
    }
}